// Round 5
// baseline (447.791 us; speedup 1.0000x reference)
//
#include <hip/hip_runtime.h>
#include <math.h>

#define NB 8
#define NS 2048
#define ND 512
#define NHH 8
#define NDH 64

typedef __attribute__((ext_vector_type(4))) float f32x4;
typedef __attribute__((ext_vector_type(8))) _Float16 f16x8;
typedef unsigned short ush;

__device__ inline unsigned pk2h(float a, float b) {   // v_cvt_pkrtz_f16_f32
    __fp16 __attribute__((ext_vector_type(2))) h = __builtin_amdgcn_cvt_pkrtz(a, b);
    unsigned r; __builtin_memcpy(&r, &h, 4); return r;
}
__device__ inline ush f2h(float f) {
    _Float16 h = (_Float16)f; ush r; __builtin_memcpy(&r, &h, 2); return r;
}
__device__ inline float h2f(ush u) {
    _Float16 h; __builtin_memcpy(&h, &u, 2); return (float)h;
}

// async global->LDS, 16B per lane (global_load_lds_dwordx4)
#define GLL16(gp, lp) __builtin_amdgcn_global_load_lds( \
    (const __attribute__((address_space(1))) unsigned int*)(gp), \
    (__attribute__((address_space(3))) unsigned int*)(lp), 16, 0, 0)

// ---------------------------------------------------------------------------
// Kernel 0: weight conversion to f16. y<3: Wq/Wk/Wv. y==3: Wo -> hi/lo f16.
// ---------------------------------------------------------------------------
__global__ __launch_bounds__(256) void conv_w_kernel(
    const float* __restrict__ Wq, const float* __restrict__ Wk,
    const float* __restrict__ Wv, const float* __restrict__ Wo,
    ush* __restrict__ wf16, ush* __restrict__ wo_hi, ush* __restrict__ wo_lo)
{
    const int y = blockIdx.y;
    const int i = (blockIdx.x * 256 + threadIdx.x) * 4;
    if (y < 3) {
        const float* src = (y == 0) ? Wq : (y == 1) ? Wk : Wv;
        const float4 v = *(const float4*)&src[i];
        ushort4 o;
        o.x = f2h(v.x); o.y = f2h(v.y); o.z = f2h(v.z); o.w = f2h(v.w);
        *(ushort4*)&wf16[y * 262144 + i] = o;
    } else {
        const float4 v = *(const float4*)&Wo[i];
        ushort4 hi, lo;
        hi.x = f2h(v.x); lo.x = f2h(v.x - h2f(hi.x));
        hi.y = f2h(v.y); lo.y = f2h(v.y - h2f(hi.y));
        hi.z = f2h(v.z); lo.z = f2h(v.z - h2f(hi.z));
        hi.w = f2h(v.w); lo.w = f2h(v.w - h2f(hi.w));
        *(ushort4*)&wo_hi[i] = hi;
        *(ushort4*)&wo_lo[i] = lo;
    }
}

// ---------------------------------------------------------------------------
// Kernel 1: QKV projections via f16 MFMA 16x16x32. 128x128 tile, BK=32.
// A (x fp32) converted in-staging via cvt_pkrtz; B (weights f16) via GLL16.
// Epilogue: z=0 Q (scaled 0.125*log2e, B,H,S,DH f16); z=1 K; z=2 V stored
// transposed (B,H,DH,S).
// ---------------------------------------------------------------------------
__global__ __launch_bounds__(256) void qkv_gemm_kernel(
    const float* __restrict__ xq, const float* __restrict__ xk, const float* __restrict__ xv,
    const ush* __restrict__ wf16,
    const float* __restrict__ bq, const float* __restrict__ bk, const float* __restrict__ bv,
    ush* __restrict__ Qb, ush* __restrict__ Kb, ush* __restrict__ VT)
{
    __shared__ ush As[4096];
    __shared__ ush Bs[4096];

    const int z = blockIdx.z;
    const float* X    = (z == 0) ? xq : (z == 1) ? xk : xv;
    const ush*   W    = wf16 + z * 262144;
    const float* bias = (z == 0) ? bq : (z == 1) ? bk : bv;

    const int t = threadIdx.x;
    const int w = t >> 6, l = t & 63;
    const int l15 = l & 15, g = l >> 4;
    const int m0 = blockIdx.x * 128, n0 = blockIdx.y * 128;
    const int wm = (w & 1) << 6, wn = (w >> 1) << 6;

    const int srow = l >> 2;
    const int sg   = (l & 3) ^ ((srow + (srow >> 2)) & 3);
    const int fsw  = (g ^ ((l15 + (l15 >> 2)) & 3)) << 3;
    const int c0   = w * 2;

    f32x4 acc[4][4];
    #pragma unroll
    for (int i = 0; i < 4; ++i)
        #pragma unroll
        for (int j = 0; j < 4; ++j) acc[i][j] = (f32x4)(0.0f);

    for (int kt = 0; kt < 512; kt += 32) {
        const size_t ar0 = (size_t)(m0 + c0 * 16 + srow) * 512 + kt + sg * 8;
        const size_t ar1 = (size_t)(m0 + (c0 + 1) * 16 + srow) * 512 + kt + sg * 8;
        const float4 a0 = *(const float4*)&X[ar0];
        const float4 a1 = *(const float4*)&X[ar0 + 4];
        const float4 a2 = *(const float4*)&X[ar1];
        const float4 a3 = *(const float4*)&X[ar1 + 4];

        __syncthreads();

        GLL16(&W[(size_t)(n0 + c0 * 16 + srow) * 512 + kt + sg * 8], &Bs[c0 * 512 + l * 8]);
        GLL16(&W[(size_t)(n0 + (c0 + 1) * 16 + srow) * 512 + kt + sg * 8], &Bs[(c0 + 1) * 512 + l * 8]);

        uint4 u0, u1;
        u0.x = pk2h(a0.x, a0.y); u0.y = pk2h(a0.z, a0.w);
        u0.z = pk2h(a1.x, a1.y); u0.w = pk2h(a1.z, a1.w);
        u1.x = pk2h(a2.x, a2.y); u1.y = pk2h(a2.z, a2.w);
        u1.z = pk2h(a3.x, a3.y); u1.w = pk2h(a3.z, a3.w);
        *(uint4*)&As[c0 * 512 + l * 8] = u0;
        *(uint4*)&As[(c0 + 1) * 512 + l * 8] = u1;

        __syncthreads();

        f16x8 af[4], bfr[4];
        #pragma unroll
        for (int mi = 0; mi < 4; ++mi)
            af[mi] = *(const f16x8*)&As[(((w & 1) << 2) + mi) * 512 + l15 * 32 + fsw];
        #pragma unroll
        for (int ni = 0; ni < 4; ++ni)
            bfr[ni] = *(const f16x8*)&Bs[(((w >> 1) << 2) + ni) * 512 + l15 * 32 + fsw];
        #pragma unroll
        for (int mi = 0; mi < 4; ++mi)
            #pragma unroll
            for (int ni = 0; ni < 4; ++ni)
                acc[mi][ni] = __builtin_amdgcn_mfma_f32_16x16x32_f16(af[mi], bfr[ni], acc[mi][ni], 0, 0, 0);
    }

    const float qscale = (z == 0) ? 0.18033688011112042f : 1.0f;   // 0.125*log2(e)
    float bnv[4];
    #pragma unroll
    for (int ni = 0; ni < 4; ++ni) bnv[ni] = bias[n0 + wn + ni * 16 + l15];

    if (z < 2) {
        ush* O = (z == 0) ? Qb : Kb;
        #pragma unroll
        for (int mi = 0; mi < 4; ++mi) {
            #pragma unroll
            for (int ni = 0; ni < 4; ++ni) {
                const int n = n0 + wn + ni * 16 + l15;
                const int hh = n >> 6, dh = n & 63;
                #pragma unroll
                for (int r = 0; r < 4; ++r) {
                    const int m = m0 + wm + mi * 16 + (g << 2) + r;
                    const int bi = m >> 11, s = m & (NS - 1);
                    O[((size_t)(bi * 8 + hh) * 2048 + s) * 64 + dh] =
                        f2h((acc[mi][ni][r] + bnv[ni]) * qscale);
                }
            }
        }
    } else {
        #pragma unroll
        for (int mi = 0; mi < 4; ++mi) {
            #pragma unroll
            for (int ni = 0; ni < 4; ++ni) {
                const int n = n0 + wn + ni * 16 + l15;
                const int hh = n >> 6, dh = n & 63;
                const int mb = m0 + wm + mi * 16 + (g << 2);
                const int bi = mb >> 11, s = mb & (NS - 1);
                uint2 pk;
                pk.x = pk2h(acc[mi][ni][0] + bnv[ni], acc[mi][ni][1] + bnv[ni]);
                pk.y = pk2h(acc[mi][ni][2] + bnv[ni], acc[mi][ni][3] + bnv[ni]);
                *(uint2*)&VT[((size_t)(bi * 8 + hh) * 64 + dh) * 2048 + s] = pk;
            }
        }
    }
}

// ---------------------------------------------------------------------------
// Kernel 2: flash attention, barrier-free key-sliced waves, f16 MFMA.
// Wave w owns keys [w*32, +32) step 128. S^T = K·Q^T (A=K, B=Q held in regs),
// exp2, P -> wave-private LDS (no barrier; wave-internal lgkmcnt ordering),
// PV with V B-frags direct from global VT (B,H,DH,S). No-max softmax =>
// partial O/l merge by addition via LDS atomicAdd at the end (one barrier).
// ---------------------------------------------------------------------------
__global__ __launch_bounds__(256, 2) void attn_kernel(
    ush* __restrict__ Qb, const ush* __restrict__ Kb,
    const ush* __restrict__ VT, const int* __restrict__ lens,
    ush* __restrict__ ctx_lo)
{
    __shared__ float Osum[64][66];       // 16.9 KB
    __shared__ float Lsum[64];
    __shared__ ush   Ps[4][64][40];      // 20.5 KB, per-wave P [w][q][key32]

    const int tid = threadIdx.x;
    const int w = tid >> 6, l = tid & 63;
    const int l15 = l & 15, g = l >> 4;

    const int id = blockIdx.x;
    const int h = id & 7, qt = (id >> 3) & 31, b = id >> 8;
    const int L = lens[b];
    const int q0 = qt << 6;
    const size_t bh = ((size_t)b * 8 + h) * 2048;

    // zero merge buffers
    {
        float* p = &Osum[0][0];
        for (int i = tid; i < 64 * 66; i += 256) p[i] = 0.0f;
        if (tid < 64) Lsum[tid] = 0.0f;
    }

    // Q B-frags, held for the whole kernel: qf[qsub][half]
    f16x8 qf[4][2];
    #pragma unroll
    for (int qs = 0; qs < 4; ++qs)
        #pragma unroll
        for (int hf = 0; hf < 2; ++hf)
            qf[qs][hf] = *(const f16x8*)&Qb[(bh + q0 + qs * 16 + l15) * 64 + hf * 32 + g * 8];

    __syncthreads();   // init visible before any wave's end-merge adds

    const ush* kB = Kb + bh * 64;
    const ush* vB = VT + (size_t)(b * 8 + h) * 64 * 2048;

    f32x4 o_[4][4];
    #pragma unroll
    for (int i = 0; i < 4; ++i)
        #pragma unroll
        for (int j = 0; j < 4; ++j) o_[i][j] = (f32x4)(0.0f);
    float lp[4] = {0.0f, 0.0f, 0.0f, 0.0f};

    int kc = w * 32;
    f16x8 kf[2][2], vf[4];
    if (kc < L) {
        #pragma unroll
        for (int st = 0; st < 2; ++st)
            #pragma unroll
            for (int hf = 0; hf < 2; ++hf)
                kf[st][hf] = *(const f16x8*)&kB[(size_t)(kc + st * 16 + l15) * 64 + hf * 32 + g * 8];
        #pragma unroll
        for (int d = 0; d < 4; ++d)
            vf[d] = *(const f16x8*)&vB[(size_t)(d * 16 + l15) * 2048 + kc + g * 8];
    }

    for (; kc < L; kc += 128) {
        // S^T[key32][q64]
        f32x4 s[2][4];
        #pragma unroll
        for (int st = 0; st < 2; ++st)
            #pragma unroll
            for (int qs = 0; qs < 4; ++qs) {
                s[st][qs] = (f32x4)(0.0f);
                s[st][qs] = __builtin_amdgcn_mfma_f32_16x16x32_f16(kf[st][0], qf[qs][0], s[st][qs], 0, 0, 0);
                s[st][qs] = __builtin_amdgcn_mfma_f32_16x16x32_f16(kf[st][1], qf[qs][1], s[st][qs], 0, 0, 0);
            }

        // prefetch next chunk (reads past region end stay inside ws; values
        // only consumed when kc+128 < L, in which case they're in-range)
        const int kn = kc + 128;
        f16x8 kfn[2][2], vfn[4];
        #pragma unroll
        for (int st = 0; st < 2; ++st)
            #pragma unroll
            for (int hf = 0; hf < 2; ++hf)
                kfn[st][hf] = *(const f16x8*)&kB[(size_t)(kn + st * 16 + l15) * 64 + hf * 32 + g * 8];
        #pragma unroll
        for (int d = 0; d < 4; ++d)
            vfn[d] = *(const f16x8*)&vB[(size_t)(d * 16 + l15) * 2048 + kn + g * 8];

        // exp2 + pack + wave-private LDS store (lane: q=qs*16+l15, keys st*16+g*4..+3)
        #pragma unroll
        for (int st = 0; st < 2; ++st) {
            const int keyb = kc + st * 16 + (g << 2);
            #pragma unroll
            for (int qs = 0; qs < 4; ++qs) {
                float p0 = (keyb + 0 < L) ? exp2f(s[st][qs][0]) : 0.0f;
                float p1 = (keyb + 1 < L) ? exp2f(s[st][qs][1]) : 0.0f;
                float p2 = (keyb + 2 < L) ? exp2f(s[st][qs][2]) : 0.0f;
                float p3 = (keyb + 3 < L) ? exp2f(s[st][qs][3]) : 0.0f;
                lp[qs] += (p0 + p1) + (p2 + p3);
                uint2 pk;
                pk.x = pk2h(p0, p1);
                pk.y = pk2h(p2, p3);
                *(uint2*)&Ps[w][qs * 16 + l15][st * 16 + (g << 2)] = pk;
            }
        }

        // P A-frags back (same wave wrote them; no barrier needed)
        f16x8 af[4];
        #pragma unroll
        for (int qs = 0; qs < 4; ++qs)
            af[qs] = *(const f16x8*)&Ps[w][qs * 16 + l15][g * 8];

        // PV: O[q][dv] += P[q][key32] * V[key32][dv]
        #pragma unroll
        for (int qs = 0; qs < 4; ++qs)
            #pragma unroll
            for (int d = 0; d < 4; ++d)
                o_[qs][d] = __builtin_amdgcn_mfma_f32_16x16x32_f16(af[qs], vf[d], o_[qs][d], 0, 0, 0);

        #pragma unroll
        for (int st = 0; st < 2; ++st)
            #pragma unroll
            for (int hf = 0; hf < 2; ++hf) kf[st][hf] = kfn[st][hf];
        #pragma unroll
        for (int d = 0; d < 4; ++d) vf[d] = vfn[d];
    }

    // merge l across g-groups, then into LDS
    #pragma unroll
    for (int qs = 0; qs < 4; ++qs) {
        float v = lp[qs];
        v += __shfl_xor(v, 16);
        v += __shfl_xor(v, 32);
        if (g == 0) atomicAdd(&Lsum[qs * 16 + l15], v);
    }
    // merge O: lane holds D rows q=qs*16+g*4+r, col dv=d*16+l15
    #pragma unroll
    for (int qs = 0; qs < 4; ++qs)
        #pragma unroll
        for (int d = 0; d < 4; ++d)
            #pragma unroll
            for (int r = 0; r < 4; ++r)
                atomicAdd(&Osum[qs * 16 + (g << 2) + r][d * 16 + l15], o_[qs][d][r]);

    __syncthreads();

    // epilogue: thread -> (q, 16-wide dv segment); ctx hi over Qb, lo separate
    const int q = tid >> 2, seg = (tid & 3) << 4;
    const float inv = 1.0f / Lsum[q];
    const size_t row = bh + q0 + q;
    ush hib[16], lob[16];
    #pragma unroll
    for (int j = 0; j < 16; ++j) {
        const float val = Osum[q][seg + j] * inv;
        const ush hi = f2h(val);
        hib[j] = hi;
        lob[j] = f2h(val - h2f(hi));
    }
    *(uint4*)&Qb[row * 64 + seg]         = *(uint4*)&hib[0];
    *(uint4*)&Qb[row * 64 + seg + 8]     = *(uint4*)&hib[8];
    *(uint4*)&ctx_lo[row * 64 + seg]     = *(uint4*)&lob[0];
    *(uint4*)&ctx_lo[row * 64 + seg + 8] = *(uint4*)&lob[8];
}

// ---------------------------------------------------------------------------
// Kernel 3: out = ctx @ Wo^T + bo, 3-term split f16 MFMA
// (hi·hi + lo·hi + hi·lo ≈ fp32 accuracy). ctx gathered from (B,H,S,DH).
// ---------------------------------------------------------------------------
__global__ __launch_bounds__(256) void out_gemm_kernel(
    const ush* __restrict__ ctx_hi, const ush* __restrict__ ctx_lo,
    const ush* __restrict__ wo_hi, const ush* __restrict__ wo_lo,
    const float* __restrict__ bo, float* __restrict__ out)
{
    __shared__ ush Ah[4096], Al[4096], Bh[4096], Bl[4096];

    const int t = threadIdx.x;
    const int w = t >> 6, l = t & 63;
    const int l15 = l & 15, g = l >> 4;
    const int m0 = blockIdx.x * 128, n0 = blockIdx.y * 128;
    const int wm = (w & 1) << 6, wn = (w >> 1) << 6;

    const int srow = l >> 2;
    const int sg   = (l & 3) ^ ((srow + (srow >> 2)) & 3);
    const int fsw  = (g ^ ((l15 + (l15 >> 2)) & 3)) << 3;
    const int c0   = w * 2;

    f32x4 acc[4][4];
    #pragma unroll
    for (int i = 0; i < 4; ++i)
        #pragma unroll
        for (int j = 0; j < 4; ++j) acc[i][j] = (f32x4)(0.0f);

    for (int kt = 0; kt < 512; kt += 32) {
        __syncthreads();
        #pragma unroll
        for (int cc = 0; cc < 2; ++cc) {
            const int c = c0 + cc;
            const int m = m0 + c * 16 + srow;
            const int k = kt + sg * 8;
            const size_t ga = ((size_t)((m >> 11) * 8 + (k >> 6)) * 2048 + (m & (NS - 1))) * 64 + (k & 63);
            GLL16(&ctx_hi[ga], &Ah[c * 512 + l * 8]);
            GLL16(&ctx_lo[ga], &Al[c * 512 + l * 8]);
            const size_t gb = (size_t)(n0 + c * 16 + srow) * 512 + kt + sg * 8;
            GLL16(&wo_hi[gb], &Bh[c * 512 + l * 8]);
            GLL16(&wo_lo[gb], &Bl[c * 512 + l * 8]);
        }
        __syncthreads();

        f16x8 ah[4], al[4], bh4[4], bl4[4];
        #pragma unroll
        for (int mi = 0; mi < 4; ++mi) {
            const int off = (((w & 1) << 2) + mi) * 512 + l15 * 32 + fsw;
            ah[mi] = *(const f16x8*)&Ah[off];
            al[mi] = *(const f16x8*)&Al[off];
        }
        #pragma unroll
        for (int ni = 0; ni < 4; ++ni) {
            const int off = (((w >> 1) << 2) + ni) * 512 + l15 * 32 + fsw;
            bh4[ni] = *(const f16x8*)&Bh[off];
            bl4[ni] = *(const f16x8*)&Bl[off];
        }
        #pragma unroll
        for (int mi = 0; mi < 4; ++mi)
            #pragma unroll
            for (int ni = 0; ni < 4; ++ni) {
                acc[mi][ni] = __builtin_amdgcn_mfma_f32_16x16x32_f16(ah[mi], bh4[ni], acc[mi][ni], 0, 0, 0);
                acc[mi][ni] = __builtin_amdgcn_mfma_f32_16x16x32_f16(al[mi], bh4[ni], acc[mi][ni], 0, 0, 0);
                acc[mi][ni] = __builtin_amdgcn_mfma_f32_16x16x32_f16(ah[mi], bl4[ni], acc[mi][ni], 0, 0, 0);
            }
    }

    float bov[4];
    #pragma unroll
    for (int ni = 0; ni < 4; ++ni) bov[ni] = bo[n0 + wn + ni * 16 + l15];

    #pragma unroll
    for (int mi = 0; mi < 4; ++mi)
        #pragma unroll
        for (int ni = 0; ni < 4; ++ni) {
            const int n = n0 + wn + ni * 16 + l15;
            #pragma unroll
            for (int r = 0; r < 4; ++r) {
                const int m = m0 + wm + mi * 16 + (g << 2) + r;
                out[(size_t)m * 512 + n] = acc[mi][ni][r] + bov[ni];
            }
        }
}

// ---------------------------------------------------------------------------
extern "C" void kernel_launch(void* const* d_in, const int* in_sizes, int n_in,
                              void* d_out, int out_size, void* d_ws, size_t ws_size,
                              hipStream_t stream)
{
    const float* xq   = (const float*)d_in[0];
    const float* xk   = (const float*)d_in[1];
    const float* xv   = (const float*)d_in[2];
    const float* Wq   = (const float*)d_in[3];
    const float* bq   = (const float*)d_in[4];
    const float* Wk   = (const float*)d_in[5];
    const float* bk   = (const float*)d_in[6];
    const float* Wv   = (const float*)d_in[7];
    const float* bv   = (const float*)d_in[8];
    const float* Wo   = (const float*)d_in[9];
    const float* bo   = (const float*)d_in[10];
    const int*   lens = (const int*)d_in[11];
    float* out = (float*)d_out;

    const size_t elems = (size_t)NB * NHH * NS * NDH;   // 8.39M
    ush* Qb     = (ush*)d_ws;          // f16 Q (pre-scaled); later ctx_hi in place
    ush* Kb     = Qb + elems;
    ush* VT     = Kb + elems;          // V transposed (B,H,DH,S)
    ush* ctx_lo = VT + elems;
    ush* wf16   = ctx_lo + elems;      // Wq,Wk,Wv f16
    ush* wo_hi  = wf16 + 3 * 262144;
    ush* wo_lo  = wo_hi + 262144;
    // total ~69.7 MB (< 100.7 MB proven in R1)

    const dim3 blk(256);
    conv_w_kernel<<<dim3(256, 4), blk, 0, stream>>>(Wq, Wk, Wv, Wo, wf16, wo_hi, wo_lo);
    qkv_gemm_kernel<<<dim3(128, 4, 3), blk, 0, stream>>>(
        xq, xk, xv, wf16, bq, bk, bv, Qb, Kb, VT);
    attn_kernel<<<dim3(NB * NHH * (NS / 64)), blk, 0, stream>>>(Qb, Kb, VT, lens, ctx_lo);
    out_gemm_kernel<<<dim3(128, 4), blk, 0, stream>>>(Qb, ctx_lo, wo_hi, wo_lo, bo, out);
}